// Round 1
// baseline (3825.055 us; speedup 1.0000x reference)
//
#include <hip/hip_runtime.h>

#define BN 40000
#define TT 12
#define EE 160000

__device__ __forceinline__ float lrelu(float v){ return v > 0.f ? v : 0.2f*v; }

// ---------------- graph preprocessing ----------------
__global__ void k_hist(const int* __restrict__ ei, int* __restrict__ degcnt, int* __restrict__ cnt){
  int e = blockIdx.x*256 + threadIdx.x;
  if (e < EE){
    atomicAdd(&degcnt[ei[e]], 1);      // src out-degree (ChebConv norm)
    atomicAdd(&cnt[ei[EE + e]], 1);    // dst in-degree (CSR)
  }
}

__global__ void k_dis(const int* __restrict__ degcnt, float* __restrict__ dis){
  int i = blockIdx.x*256 + threadIdx.x;
  if (i < BN){ int d = degcnt[i]; dis[i] = d > 0 ? rsqrtf((float)d) : 0.f; }
}

__global__ void k_scan(const int* __restrict__ cnt, int* __restrict__ rowptr, int* __restrict__ cursor){
  __shared__ int part[1024];
  int tid = threadIdx.x;
  const int CH = 40;                   // 1024*40 >= 40000
  int base = tid*CH;
  int s = 0;
  for (int j=0;j<CH;++j){ int idx=base+j; if (idx<BN) s += cnt[idx]; }
  part[tid] = s; __syncthreads();
  for (int off=1; off<1024; off<<=1){
    int v = (tid>=off)? part[tid-off] : 0;
    __syncthreads();
    part[tid] += v;
    __syncthreads();
  }
  int run = part[tid] - s;             // exclusive base
  for (int j=0;j<CH;++j){ int idx=base+j; if (idx<BN){ rowptr[idx]=run; cursor[idx]=run; run += cnt[idx]; } }
  if (tid==1023) rowptr[BN] = part[1023];
}

__global__ void k_scatter(const int* __restrict__ ei, const float* __restrict__ dis,
                          int* __restrict__ cursor, int* __restrict__ esrc, float* __restrict__ ew){
  int e = blockIdx.x*256 + threadIdx.x;
  if (e < EE){
    int s = ei[e], d = ei[EE+e];
    int p = atomicAdd(&cursor[d], 1);
    esrc[p] = s;
    ew[p] = -dis[s]*dis[d];
  }
}

// ---------------- Cheb propagation (FIN=1 scalars) ----------------
__global__ void k_prop1(const float* __restrict__ x, const int* __restrict__ rowptr,
                        const int* __restrict__ esrc, const float* __restrict__ ew,
                        float* __restrict__ tx1){
  int i = blockIdx.x*256 + threadIdx.x;
  if (i >= BN*TT) return;
  int d = i/TT, t = i - d*TT;
  int r0 = rowptr[d], r1 = rowptr[d+1];
  float a = 0.f;
  for (int p=r0;p<r1;++p) a += ew[p]*x[esrc[p]*TT + t];
  tx1[i] = a;
}

__global__ void k_prop2(const float* __restrict__ x, const float* __restrict__ tx1,
                        const int* __restrict__ rowptr, const int* __restrict__ esrc,
                        const float* __restrict__ ew, float* __restrict__ tx2){
  int i = blockIdx.x*256 + threadIdx.x;
  if (i >= BN*TT) return;
  int d = i/TT, t = i - d*TT;
  int r0 = rowptr[d], r1 = rowptr[d+1];
  float a = 0.f;
  for (int p=r0;p<r1;++p) a += ew[p]*tx1[esrc[p]*TT + t];
  tx2[i] = 2.f*a - x[i];
}

// ---------------- fold cheb_w/cheb_b through gat_w / att vectors ----------------
// gwbuf layout: [k*128+hc] k<3 (384) | gc 384..511 | ask 512+k*2+h | adk 518+k*2+h | asc 524+h | adc 526+h
__global__ void k_precomp(const float* __restrict__ cheb_w, const float* __restrict__ cheb_b,
                          const float* __restrict__ gat_w, const float* __restrict__ att_src,
                          const float* __restrict__ att_dst, float* __restrict__ gwbuf){
  __shared__ float sgw[384]; __shared__ float sgc[128];
  int hc = threadIdx.x; // 128 threads
  for (int k=0;k<3;++k){
    float a=0; for (int c=0;c<64;++c) a += cheb_w[k*64+c]*gat_w[hc*64+c];
    sgw[k*128+hc]=a; gwbuf[k*128+hc]=a;
  }
  { float g=0; for (int c=0;c<64;++c) g += cheb_b[c]*gat_w[hc*64+c]; sgc[hc]=g; gwbuf[384+hc]=g; }
  __syncthreads();
  if (hc<6){ int k=hc>>1, h=hc&1; float a=0,d=0;
    for (int c=0;c<64;++c){ float g=sgw[k*128+h*64+c]; a+=g*att_src[h*64+c]; d+=g*att_dst[h*64+c]; }
    gwbuf[512+hc]=a; gwbuf[518+hc]=d; }
  if (hc<2){ float a=0,d=0;
    for (int c=0;c<64;++c){ float g=sgc[hc*64+c]; a+=g*att_src[hc*64+c]; d+=g*att_dst[hc*64+c]; }
    gwbuf[524+hc]=a; gwbuf[526+hc]=d; }
}

// ---------------- GAT: one wave per (node,t), lane = feature ----------------
__global__ __launch_bounds__(256) void k_gat(const float* __restrict__ x, const float* __restrict__ tx1,
     const float* __restrict__ tx2, const int* __restrict__ rowptr, const int* __restrict__ esrc,
     const float* __restrict__ gwbuf, const float* __restrict__ gat_b, float* __restrict__ sp){
  int wave = (blockIdx.x<<2) + (threadIdx.x>>6);
  int lane = threadIdx.x & 63;
  int d = wave/TT, t = wave - d*TT;

  float ga0 = gwbuf[lane],      ga1 = gwbuf[128+lane], ga2 = gwbuf[256+lane], gac = gwbuf[384+lane];
  float gb0 = gwbuf[64+lane],   gb1 = gwbuf[192+lane], gb2 = gwbuf[320+lane], gbc = gwbuf[448+lane];
  float as00=gwbuf[512], as01=gwbuf[513], as10=gwbuf[514], as11=gwbuf[515], as20=gwbuf[516], as21=gwbuf[517];
  float ad00=gwbuf[518], ad01=gwbuf[519], ad10=gwbuf[520], ad11=gwbuf[521], ad20=gwbuf[522], ad21=gwbuf[523];
  float asc0=gwbuf[524], asc1=gwbuf[525], adc0=gwbuf[526], adc1=gwbuf[527];

  int r0 = rowptr[d], r1 = rowptr[d+1];
  float td0 = x[d*TT+t], td1 = tx1[d*TT+t], td2 = tx2[d*TT+t];
  float adh0 = td0*ad00 + td1*ad10 + td2*ad20 + adc0;
  float adh1 = td0*ad01 + td1*ad11 + td2*ad21 + adc1;
  float es0 = lrelu(td0*as00 + td1*as10 + td2*as20 + asc0 + adh0);   // self loop
  float es1 = lrelu(td0*as01 + td1*as11 + td2*as21 + asc1 + adh1);
  float m0 = es0, m1 = es1;
  for (int p=r0;p<r1;++p){
    int s = esrc[p];
    float s0 = x[s*TT+t], s1 = tx1[s*TT+t], s2 = tx2[s*TT+t];
    m0 = fmaxf(m0, lrelu(s0*as00 + s1*as10 + s2*as20 + asc0 + adh0));
    m1 = fmaxf(m1, lrelu(s0*as01 + s1*as11 + s2*as21 + asc1 + adh1));
  }
  float z0, z1, acc0, acc1;
  { float p0 = __expf(es0 - m0), p1 = __expf(es1 - m1);
    z0 = p0; z1 = p1;
    acc0 = p0*(td0*ga0 + td1*ga1 + td2*ga2 + gac);
    acc1 = p1*(td0*gb0 + td1*gb1 + td2*gb2 + gbc); }
  for (int p=r0;p<r1;++p){
    int s = esrc[p];
    float s0 = x[s*TT+t], s1 = tx1[s*TT+t], s2 = tx2[s*TT+t];
    float e0 = lrelu(s0*as00 + s1*as10 + s2*as20 + asc0 + adh0);
    float e1 = lrelu(s0*as01 + s1*as11 + s2*as21 + asc1 + adh1);
    float p0 = __expf(e0 - m0), p1 = __expf(e1 - m1);
    z0 += p0; z1 += p1;
    acc0 += p0*(s0*ga0 + s1*ga1 + s2*ga2 + gac);
    acc1 += p1*(s0*gb0 + s1*gb1 + s2*gb2 + gbc);
  }
  sp[wave*64 + lane] = 0.5f*(acc0/z0 + acc1/z1) + gat_b[lane];
}

// ---------------- fused temporal pipeline helpers ----------------
__device__ __forceinline__ void conv_tap(const float a[12], float w0, float w1, float w2, float acc[12]){
  #pragma unroll
  for (int t=0;t<12;++t) acc[t] += a[t]*w1;
  #pragma unroll
  for (int t=1;t<12;++t) acc[t] += a[t-1]*w0;
  #pragma unroll
  for (int t=0;t<11;++t) acc[t] += a[t+1]*w2;
}

// processes 8 local columns starting at cl0 of a 32-wide chunk starting at global col cbase
__device__ __forceinline__ void conv_chunk(float (* __restrict__ s_in)[64], const float* __restrict__ wl,
                                           int cl0, int cbase, float acc[12]){
  for (int cb=0; cb<8; cb+=4){
    int cl = cl0 + cb;
    float a0[12],a1[12],a2[12],a3[12];
    #pragma unroll
    for (int t=0;t<12;++t){
      float4 v = *(const float4*)&s_in[t][cbase + cl];
      a0[t]=v.x; a1[t]=v.y; a2[t]=v.z; a3[t]=v.w;
    }
    conv_tap(a0, wl[(cl+0)*3+0], wl[(cl+0)*3+1], wl[(cl+0)*3+2], acc);
    conv_tap(a1, wl[(cl+1)*3+0], wl[(cl+1)*3+1], wl[(cl+1)*3+2], acc);
    conv_tap(a2, wl[(cl+2)*3+0], wl[(cl+2)*3+1], wl[(cl+2)*3+2], acc);
    conv_tap(a3, wl[(cl+3)*3+0], wl[(cl+3)*3+1], wl[(cl+3)*3+2], acc);
  }
}

__device__ __forceinline__ void qkv_chunk(float (* __restrict__ s_in)[64], const float* __restrict__ wb,
                                          int j, int kbase, float acc[12]){
  for (int kb=0; kb<32; kb+=4){
    float a0[12],a1[12],a2[12],a3[12];
    #pragma unroll
    for (int t=0;t<12;++t){
      float4 v = *(const float4*)&s_in[t][kbase + kb];
      a0[t]=v.x; a1[t]=v.y; a2[t]=v.z; a3[t]=v.w;
    }
    float w0 = wb[(kb+0)*193 + j], w1 = wb[(kb+1)*193 + j];
    float w2 = wb[(kb+2)*193 + j], w3 = wb[(kb+3)*193 + j];
    #pragma unroll
    for (int t=0;t<12;++t) acc[t] += a0[t]*w0 + a1[t]*w1 + a2[t]*w2 + a3[t]*w3;
  }
}

// ---------------- fused temporal: tc conv -> MHA -> residual+LN -> bc/fc convs ----------------
__global__ __launch_bounds__(256) void k_temporal(
  const float* __restrict__ sp, const float* __restrict__ x,
  const float* __restrict__ tc_w, const float* __restrict__ tc_b,
  const float* __restrict__ in_w, const float* __restrict__ in_b,
  const float* __restrict__ out_w, const float* __restrict__ out_b,
  const float* __restrict__ res_w, const float* __restrict__ res_b,
  const float* __restrict__ ln_g, const float* __restrict__ ln_b,
  const float* __restrict__ bc_w, const float* __restrict__ bc_b,
  const float* __restrict__ fc_w, const float* __restrict__ fc_b,
  float* __restrict__ out)
{
  __shared__ __align__(16) float wbuf[6208];      // padded weight stage
  __shared__ __align__(16) float s_a[12][64];     // sp, later attention output o
  __shared__ __align__(16) float s_b[12][64];     // tc, later bc accumulator
  __shared__ __align__(16) float s_r[12][64];     // LN result
  __shared__ __align__(16) float s_qkv[12*193];   // qkv (padded), later fc accumulator
  __shared__ float s_red1[12][16], s_red2[12][16];
  __shared__ float s_mu[12], s_iv[12];

  const int nd = blockIdx.x;
  const int tid = threadIdx.x;
  const int o = tid & 63, cq = tid >> 6;

  // P0: load sp row, stage tc_w chunk0 ([o][97], cd=c*3+dt, c<32), init s_b = tc_b
  for (int i=tid;i<768;i+=256) s_a[0][i] = sp[nd*768 + i];
  for (int i=tid;i<6144;i+=256){ int oo=i/96, cd=i%96; wbuf[oo*97+cd] = tc_w[oo*192+cd]; }
  for (int i=tid;i<768;i+=256) s_b[0][i] = tc_b[i&63];
  __syncthreads();

  float acc[12];
  #pragma unroll
  for (int t=0;t<12;++t) acc[t]=0.f;
  conv_chunk(s_a, &wbuf[o*97], cq*8, 0, acc);
  __syncthreads();
  for (int i=tid;i<6144;i+=256){ int oo=i/96, cd=i%96; wbuf[oo*97+cd] = tc_w[oo*192+96+cd]; }
  __syncthreads();
  conv_chunk(s_a, &wbuf[o*97], cq*8, 32, acc);
  #pragma unroll
  for (int t=0;t<12;++t) atomicAdd(&s_b[t][o], acc[t]);
  __syncthreads();

  // QKV: wbuf[k][193], k-chunks of 32
  for (int i=tid;i<6144;i+=256){ int j=i/32, k=i%32; wbuf[k*193+j] = in_w[j*64+k]; }
  __syncthreads();
  float qacc[12];
  if (tid < 192){
    #pragma unroll
    for (int t=0;t<12;++t) qacc[t] = in_b[tid];
    qkv_chunk(s_b, wbuf, tid, 0, qacc);
  }
  __syncthreads();
  for (int i=tid;i<6144;i+=256){ int j=i/32, k=i%32; wbuf[k*193+j] = in_w[j*64+32+k]; }
  __syncthreads();
  if (tid < 192){
    qkv_chunk(s_b, wbuf, tid, 32, qacc);
    #pragma unroll
    for (int t=0;t<12;++t) s_qkv[t*193+tid] = qacc[t];
  }
  __syncthreads();

  // stage out_w [k][65] + attention (NH=4, dh=16, T=12)
  for (int i=tid;i<4096;i+=256){ int oo=i/64, k=i%64; wbuf[k*65+oo] = out_w[i]; }
  if (tid < 48){
    int q = tid>>2, h = tid&3, hb = h*16;
    float qv[16];
    #pragma unroll
    for (int dd=0; dd<16; ++dd) qv[dd] = s_qkv[q*193 + hb + dd];
    float scv[12]; float mx = -1e30f;
    #pragma unroll
    for (int k2=0;k2<12;++k2){
      float s=0;
      #pragma unroll
      for (int dd=0;dd<16;++dd) s += qv[dd]*s_qkv[k2*193 + 64 + hb + dd];
      s *= 0.25f;
      scv[k2]=s; mx=fmaxf(mx,s);
    }
    float z=0;
    #pragma unroll
    for (int k2=0;k2<12;++k2){ float p=__expf(scv[k2]-mx); scv[k2]=p; z+=p; }
    float inv = 1.f/z;
    #pragma unroll
    for (int dd=0;dd<16;++dd){
      float a=0;
      #pragma unroll
      for (int k2=0;k2<12;++k2) a += scv[k2]*s_qkv[k2*193 + 128 + hb + dd];
      s_a[q][hb+dd] = a*inv;          // s_o aliased onto s_a
    }
  }
  __syncthreads();

  // out proj + residual + relu -> s_r (raw)
  for (int r=0;r<3;++r){
    int idx = tid + (r<<8); int t = idx>>6, oo = idx&63;
    float a = out_b[oo];
    for (int kb=0;kb<64;kb+=4){
      float4 v = *(const float4*)&s_a[t][kb];
      a += v.x*wbuf[(kb+0)*65+oo] + v.y*wbuf[(kb+1)*65+oo]
         + v.z*wbuf[(kb+2)*65+oo] + v.w*wbuf[(kb+3)*65+oo];
    }
    float zr = a + x[nd*12+t]*res_w[oo] + res_b[oo];
    s_r[t][oo] = zr > 0.f ? zr : 0.f;
  }
  __syncthreads();

  // LayerNorm over features
  if (tid < 192){
    int t = tid>>4, g = tid&15;
    float4 v = *(const float4*)&s_r[t][g*4];
    s_red1[t][g] = v.x+v.y+v.z+v.w;
    s_red2[t][g] = v.x*v.x+v.y*v.y+v.z*v.z+v.w*v.w;
  }
  __syncthreads();
  if (tid < 12){
    float s=0,q=0;
    #pragma unroll
    for (int g=0;g<16;++g){ s+=s_red1[tid][g]; q+=s_red2[tid][g]; }
    float mu = s*(1.f/64.f), var = q*(1.f/64.f) - mu*mu;
    s_mu[tid]=mu; s_iv[tid]=rsqrtf(fmaxf(var,0.f)+1e-5f);
  }
  __syncthreads();
  // normalize s_r in place + stage bc chunk0 + init s_b = bc_b
  for (int r=0;r<3;++r){
    int idx = tid + (r<<8); int t = idx>>6, oo = idx&63;
    s_r[t][oo] = (s_r[t][oo]-s_mu[t])*s_iv[t]*ln_g[oo] + ln_b[oo];
  }
  for (int i=tid;i<6144;i+=256){ int oo=i/96, cd=i%96; wbuf[oo*97+cd] = bc_w[oo*192+cd]; }
  for (int i=tid;i<768;i+=256) s_b[0][i] = bc_b[i&63];
  __syncthreads();

  // backcast conv
  #pragma unroll
  for (int t=0;t<12;++t) acc[t]=0.f;
  conv_chunk(s_r, &wbuf[o*97], cq*8, 0, acc);
  __syncthreads();
  for (int i=tid;i<6144;i+=256){ int oo=i/96, cd=i%96; wbuf[oo*97+cd] = bc_w[oo*192+96+cd]; }
  __syncthreads();
  conv_chunk(s_r, &wbuf[o*97], cq*8, 32, acc);
  #pragma unroll
  for (int t=0;t<12;++t) atomicAdd(&s_b[t][o], acc[t]);
  __syncthreads();

  // write backcast + stage fc chunk0 + init fc accumulator (reuse s_qkv[0..768))
  for (int i=tid;i<768;i+=256){ int oo=i/12, t=i-oo*12; out[(size_t)nd*768 + i] = s_b[t][oo]; }
  for (int i=tid;i<6144;i+=256){ int oo=i/96, cd=i%96; wbuf[oo*97+cd] = fc_w[oo*192+cd]; }
  for (int i=tid;i<768;i+=256) s_qkv[i] = fc_b[i&63];
  __syncthreads();

  // forecast conv
  #pragma unroll
  for (int t=0;t<12;++t) acc[t]=0.f;
  conv_chunk(s_r, &wbuf[o*97], cq*8, 0, acc);
  __syncthreads();
  for (int i=tid;i<6144;i+=256){ int oo=i/96, cd=i%96; wbuf[oo*97+cd] = fc_w[oo*192+96+cd]; }
  __syncthreads();
  conv_chunk(s_r, &wbuf[o*97], cq*8, 32, acc);
  #pragma unroll
  for (int t=0;t<12;++t) atomicAdd(&s_qkv[t*64+o], acc[t]);
  __syncthreads();
  for (int i=tid;i<768;i+=256){ int oo=i/12, t=i-oo*12; out[30720000 + (size_t)nd*768 + i] = s_qkv[t*64+oo]; }
}

// ---------------- host ----------------
extern "C" void kernel_launch(void* const* d_in, const int* in_sizes, int n_in,
                              void* d_out, int out_size, void* d_ws, size_t ws_size,
                              hipStream_t stream){
  const float* x      = (const float*)d_in[0];
  const int*   ei     = (const int*)d_in[1];
  const float* cheb_w = (const float*)d_in[2];
  const float* cheb_b = (const float*)d_in[3];
  const float* gat_w  = (const float*)d_in[4];
  const float* att_src= (const float*)d_in[5];
  const float* att_dst= (const float*)d_in[6];
  const float* gat_b  = (const float*)d_in[7];
  const float* tc_w   = (const float*)d_in[8];
  const float* tc_b   = (const float*)d_in[9];
  const float* in_w   = (const float*)d_in[10];
  const float* in_b   = (const float*)d_in[11];
  const float* out_w  = (const float*)d_in[12];
  const float* out_b  = (const float*)d_in[13];
  const float* res_w  = (const float*)d_in[14];
  const float* res_b  = (const float*)d_in[15];
  const float* ln_g   = (const float*)d_in[16];
  const float* ln_b   = (const float*)d_in[17];
  const float* bc_w   = (const float*)d_in[18];
  const float* bc_b   = (const float*)d_in[19];
  const float* fc_w   = (const float*)d_in[20];
  const float* fc_b   = (const float*)d_in[21];
  float* out = (float*)d_out;

  char* w = (char*)d_ws;
  size_t off = 0;
  auto alloc = [&](size_t bytes)->void*{ void* p = w + off; off += (bytes + 255) & ~(size_t)255; return p; };
  int*   degcnt = (int*)alloc((size_t)BN*4);
  int*   cnt    = (int*)alloc((size_t)BN*4);
  int*   rowptr = (int*)alloc((size_t)(BN+1)*4);
  int*   cursor = (int*)alloc((size_t)BN*4);
  int*   esrc   = (int*)alloc((size_t)EE*4);
  float* ew     = (float*)alloc((size_t)EE*4);
  float* tx1    = (float*)alloc((size_t)BN*TT*4);
  float* tx2    = (float*)alloc((size_t)BN*TT*4);
  float* gwb    = (float*)alloc(1024*4);
  float* dis    = (float*)alloc((size_t)BN*4);
  float* sp     = (float*)alloc((size_t)BN*TT*64*4);
  if (off > ws_size){
    // fallback: stash sp in the backcast half of d_out; k_temporal reads each node's
    // sp window before overwriting it with that node's backcast (disjoint per block).
    sp = out;
  }

  hipMemsetAsync(degcnt, 0, (size_t)BN*4, stream);
  hipMemsetAsync(cnt,    0, (size_t)BN*4, stream);
  k_hist   <<<(EE+255)/256, 256, 0, stream>>>(ei, degcnt, cnt);
  k_dis    <<<(BN+255)/256, 256, 0, stream>>>(degcnt, dis);
  k_scan   <<<1, 1024, 0, stream>>>(cnt, rowptr, cursor);
  k_scatter<<<(EE+255)/256, 256, 0, stream>>>(ei, dis, cursor, esrc, ew);
  k_prop1  <<<(BN*TT+255)/256, 256, 0, stream>>>(x, rowptr, esrc, ew, tx1);
  k_prop2  <<<(BN*TT+255)/256, 256, 0, stream>>>(x, tx1, rowptr, esrc, ew, tx2);
  k_precomp<<<1, 128, 0, stream>>>(cheb_w, cheb_b, gat_w, att_src, att_dst, gwb);
  k_gat    <<<BN*TT/4, 256, 0, stream>>>(x, tx1, tx2, rowptr, esrc, gwb, gat_b, sp);
  k_temporal<<<BN, 256, 0, stream>>>(sp, x, tc_w, tc_b, in_w, in_b, out_w, out_b,
                                     res_w, res_b, ln_g, ln_b, bc_w, bc_b, fc_w, fc_b, out);
}